// Round 8
// baseline (142.882 us; speedup 1.0000x reference)
//
#include <hip/hip_runtime.h>
#include <hip/hip_bf16.h>

typedef __bf16 bf16x8 __attribute__((ext_vector_type(8)));
typedef float  f32x4  __attribute__((ext_vector_type(4)));

#define N_TOT  8192
#define B_HALF 4096
#define D      256
// exp(sim) = exp2(dot * 10*log2(e)); zn prescaled by sqrt(10*log2(e))
#define SQK1   3.79828254f
#define LN2    0.6931471805599453f

#define RB      128   // rows per block (4 waves x 32)
#define WROWS   32    // rows per wave (2 rowtiles of 16)
#define CB      32    // cols per LDS stage
#define SLICE   512   // cols per block
#define NSLICE  16
#define NSTAGE  16    // SLICE/CB

// ---------------- kernel 1: concat + L2-normalize -> bf16 (prescaled) ----------------
__global__ __launch_bounds__(256) void normalize_kernel(
    const float* __restrict__ zi, const float* __restrict__ zj,
    ushort* __restrict__ zn, float* __restrict__ out)
{
    if (blockIdx.x == 0 && threadIdx.x == 0) *out = 0.0f;   // zero accumulator (stream-ordered)
    int row  = (blockIdx.x * 256 + threadIdx.x) >> 6;       // one wave per row
    int lane = threadIdx.x & 63;
    const float* src = (row < B_HALF) ? (zi + (size_t)row * D)
                                      : (zj + (size_t)(row - B_HALF) * D);
    float4 v = ((const float4*)src)[lane];
    float ss = v.x * v.x + v.y * v.y + v.z * v.z + v.w * v.w;
    #pragma unroll
    for (int m = 1; m < 64; m <<= 1) ss += __shfl_xor(ss, m);
    float r = SQK1 / fmaxf(sqrtf(ss), 1e-8f);               // fold exp2-scale into data
    union { ushort4 u4; __hip_bfloat16 h[4]; } o;
    o.h[0] = __float2bfloat16(v.x * r);
    o.h[1] = __float2bfloat16(v.y * r);
    o.h[2] = __float2bfloat16(v.z * r);
    o.h[3] = __float2bfloat16(v.w * r);
    ((ushort4*)zn)[(size_t)row * (D / 4) + lane] = o.u4;
}

// ---------------- kernel 2: fused sim + sum-of-exp ----------------
// grid (64,16): 128 rows x 512 cols per 256-thr block; 4 blocks/CU, 4 waves/SIMD.
// Register budget (the r5-r7 lesson: compiler caps at ~120 VGPR, spills beyond):
//   A-hoist a[2][8]=64 + acc 16 + srow 8 + st 16 + addr ~15 = ~119 -> NO spill.
// 16x16x32 MFMA, 2 rowtiles x 2 coltiles: each B-frag ds_read_b128 feeds 2 MFMAs.
// Linear LDS [32][256] with XOR swizzle (byte ^= (col&7)<<4) on write AND read:
// both sides desk-checked to 2 lanes/bank (free, m136).
__global__ __launch_bounds__(256) void fused_kernel(
    const ushort* __restrict__ zn,
    float* __restrict__ spartial,   // [N_TOT][NSLICE]
    float* __restrict__ posdot)     // [N_TOT] prescaled dot (= 10*log2(e)*cos)
{
    __shared__ ushort lds[2][CB * 256];   // 2 x 16 KiB

    int tid  = threadIdx.x;
    int lane = tid & 63;
    int w    = tid >> 6;             // 0..3
    int l15  = lane & 15;
    int l4   = lane >> 4;            // 0..3 (k-quarter)
    int r0   = blockIdx.x * RB + w * WROWS;
    int cs0  = blockIdx.y * SLICE;

    // hoist A: 32 rows x K=256 (2 rowtiles x 8 k-chunks x bf16x8) = 64 VGPRs
    bf16x8 a[2][8];
    #pragma unroll
    for (int rt = 0; rt < 2; ++rt) {
        const ushort* ar = zn + (size_t)(r0 + rt * 16 + l15) * D + l4 * 8;
        #pragma unroll
        for (int kc = 0; kc < 8; ++kc)
            a[rt][kc] = *(const bf16x8*)(ar + kc * 32);
    }

    float srow[2][4];
    #pragma unroll
    for (int rt = 0; rt < 2; ++rt)
        #pragma unroll
        for (int g = 0; g < 4; ++g) srow[rt][g] = 0.f;

    // staging helpers: chunk = tid + i*256 covers 32 cols x 32 16B-chunks
    // swizzled write: ushort idx = col*256 + (k16*8 ^ ((col&7)<<3))
    uint4 st[4];
    #pragma unroll
    for (int i = 0; i < 4; ++i) {
        int chunk = tid + i * 256;
        st[i] = *(const uint4*)(zn + (size_t)(cs0 + (chunk >> 5)) * D + (chunk & 31) * 8);
    }
    #pragma unroll
    for (int i = 0; i < 4; ++i) {
        int chunk = tid + i * 256;
        int col = chunk >> 5, k16 = chunk & 31;
        *(uint4*)(&lds[0][col * 256 + ((k16 * 8) ^ ((col & 7) << 3))]) = st[i];
    }
    __syncthreads();

    int swzr = (lane & 7) << 3;      // read-side XOR (ushort units)

    for (int s = 0; s < NSTAGE; ++s) {
        int cur = s & 1;
        if (s + 1 < NSTAGE) {        // prefetch next stage into regs (hides L2 latency)
            #pragma unroll
            for (int i = 0; i < 4; ++i) {
                int chunk = tid + i * 256;
                st[i] = *(const uint4*)(zn + (size_t)(cs0 + (s + 1) * CB + (chunk >> 5)) * D + (chunk & 31) * 8);
            }
        }

        f32x4 acc[2][2] = {};
        __builtin_amdgcn_s_setprio(1);
        #pragma unroll
        for (int kc = 0; kc < 8; ++kc) {
            #pragma unroll
            for (int ct = 0; ct < 2; ++ct) {
                int col = ct * 16 + l15;
                bf16x8 b = *(const bf16x8*)(&lds[cur][col * 256 + ((kc * 32 + l4 * 8) ^ swzr)]);
                acc[0][ct] = __builtin_amdgcn_mfma_f32_16x16x32_bf16(a[0][kc], b, acc[0][ct], 0, 0, 0);
                acc[1][ct] = __builtin_amdgcn_mfma_f32_16x16x32_bf16(a[1][kc], b, acc[1][ct], 0, 0, 0);
            }
        }
        __builtin_amdgcn_s_setprio(0);

        // epilogue: C layout col=lane&15, row=l4*4+g (m89/m91)
        #pragma unroll
        for (int rt = 0; rt < 2; ++rt) {
            int rowb = r0 + rt * 16;
            #pragma unroll
            for (int ct = 0; ct < 2; ++ct) {
                int colb = cs0 + s * CB + ct * 16;
                bool isdiag = (rowb == colb);
                bool ispos  = ((rowb ^ B_HALF) == colb);
                if (isdiag) {
                    #pragma unroll
                    for (int g = 0; g < 4; ++g) {
                        int rl = l4 * 4 + g;
                        float e = exp2f(acc[rt][ct][g]);
                        srow[rt][g] += (rl != l15) ? e : 0.0f;   // mask self-sim
                    }
                } else if (ispos) {
                    #pragma unroll
                    for (int g = 0; g < 4; ++g) {
                        int rl = l4 * 4 + g;
                        if (rl == l15) posdot[rowb + rl] = acc[rt][ct][g];  // unique writer
                        srow[rt][g] += exp2f(acc[rt][ct][g]);
                    }
                } else {
                    #pragma unroll
                    for (int g = 0; g < 4; ++g)
                        srow[rt][g] += exp2f(acc[rt][ct][g]);
                }
            }
        }

        if (s + 1 < NSTAGE) {
            __syncthreads();         // everyone done reading lds[cur^1] (stage s-1)
            #pragma unroll
            for (int i = 0; i < 4; ++i) {
                int chunk = tid + i * 256;
                int col = chunk >> 5, k16 = chunk & 31;
                *(uint4*)(&lds[cur ^ 1][col * 256 + ((k16 * 8) ^ ((col & 7) << 3))]) = st[i];
            }
            __syncthreads();
        }
    }

    // reduce each row's partials over the 16 column-lanes (xor within lane&15)
    #pragma unroll
    for (int rt = 0; rt < 2; ++rt) {
        #pragma unroll
        for (int g = 0; g < 4; ++g) {
            float v = srow[rt][g];
            v += __shfl_xor(v, 1);
            v += __shfl_xor(v, 2);
            v += __shfl_xor(v, 4);
            v += __shfl_xor(v, 8);
            if (l15 == 0) {
                int row = r0 + rt * 16 + l4 * 4 + g;
                spartial[(size_t)row * NSLICE + blockIdx.y] = v;
            }
        }
    }
}

// ---------------- kernel 3: finalize ----------------
__global__ __launch_bounds__(256) void finalize_kernel(
    const float* __restrict__ spartial, const float* __restrict__ posdot,
    float* __restrict__ out)
{
    int i    = blockIdx.x * 256 + threadIdx.x;   // row 0..8191
    int lane = threadIdx.x & 63;
    int wv   = threadIdx.x >> 6;
    float ssum = 0.f;
    #pragma unroll
    for (int k = 0; k < NSLICE; ++k) ssum += spartial[(size_t)i * NSLICE + k];
    float loss = LN2 * (log2f(ssum) - posdot[i]);
    #pragma unroll
    for (int m = 1; m < 64; m <<= 1) loss += __shfl_xor(loss, m);
    __shared__ float red[4];
    if (lane == 0) red[wv] = loss;
    __syncthreads();
    if (threadIdx.x == 0) {
        float t = red[0] + red[1] + red[2] + red[3];
        atomicAdd(out, t * (1.0f / (float)N_TOT));
    }
}

extern "C" void kernel_launch(void* const* d_in, const int* in_sizes, int n_in,
                              void* d_out, int out_size, void* d_ws, size_t ws_size,
                              hipStream_t stream)
{
    const float* zi = (const float*)d_in[0];
    const float* zj = (const float*)d_in[1];
    float* out = (float*)d_out;

    ushort* zn       = (ushort*)d_ws;                                             // 4 MiB
    float*  posdot   = (float*)((char*)d_ws + (size_t)N_TOT * D * 2);             // 32 KiB
    float*  spartial = (float*)((char*)d_ws + (size_t)N_TOT * D * 2 + N_TOT * 4); // 512 KiB

    normalize_kernel<<<N_TOT / 4, 256, 0, stream>>>(zi, zj, zn, out);

    dim3 grid2(N_TOT / RB, NSLICE);
    fused_kernel<<<grid2, 256, 0, stream>>>(zn, spartial, posdot);

    finalize_kernel<<<N_TOT / 256, 256, 0, stream>>>(spartial, posdot, out);
}